// Round 7
// baseline (594.975 us; speedup 1.0000x reference)
//
#include <hip/hip_runtime.h>
#include <math.h>

#define NB 32
#define NT 512
#define NC 4233
#define NU 64
#define LABT 129            // 2*NU+1
#define PADV (-3.4028234663852886e38f)   // float32 min (matches jnp.finfo(f32).min)

typedef float f32x4 __attribute__((ext_vector_type(4)));

// ---------------------------------------------------------------------------
// Kernel 0: emission gather (prep folded in).  UNCHANGED (verified r5/r6).
// oddS[b][t4][l] (float4 over k=0..3): logit[b][4*t4+k][oddcol(l)]
// blankS[b][t] = logit[b][t][blank]  (emission for ALL even j and j=128).
// ---------------------------------------------------------------------------
__global__ __launch_bounds__(256)
void ctc_gather_kernel(const float* __restrict__ logit,   // [B][T][C]
                       const int*   __restrict__ label,   // [U][B]
                       const int*   __restrict__ blank_ptr,
                       float4*      __restrict__ oddS,    // [B*128][64]
                       float*       __restrict__ blankS)  // [B][T]
{
    int tid = blockIdx.x * 256 + threadIdx.x;   // 262144 threads
    int l   = tid & 63;
    int bt4 = tid >> 6;        // b*128 + t4
    int b   = bt4 >> 7;
    int t4  = bt4 & 127;
    int blank = blank_ptr[0];

    int raw = label[l * NB + b];
    int ev  = (raw == blank) ? -1 : raw;
    int col = ev % NC;                 // python floor-mod for -1 pad labels
    if (col < 0) col += NC;

    const float* lg = logit + ((size_t)b * NT + (size_t)t4 * 4) * NC;
    float4 o;
    o.x = lg[col];
    o.y = lg[NC + col];
    o.z = lg[2 * NC + col];
    o.w = lg[3 * NC + col];
    oddS[(size_t)bt4 * 64 + l] = o;

    if (l == 0) {
        float4 bl;
        bl.x = lg[blank];
        bl.y = lg[NC + blank];
        bl.z = lg[2 * NC + blank];
        bl.w = lg[3 * NC + blank];
        *(float4*)&blankS[(size_t)b * NT + t4 * 4] = bl;
    }
}

// ---------------------------------------------------------------------------
// Cross-lane shift-by-1 via DPP wave_shr:1 -- pure VALU, no lgkmcnt.
// ---------------------------------------------------------------------------
__device__ __forceinline__ float dpp_wave_shr1(float x, float fill) {
    return __int_as_float(__builtin_amdgcn_update_dpp(
        __float_as_int(fill), __float_as_int(x), 0x138 /*wave_shr:1*/,
        0xf, 0xf, false));
}

// ---------------------------------------------------------------------------
// Kernel 1: single-wave DP scan; emissions double-buffered in 32 NAMED f32x4
// registers (r6's arrays went to scratch because asm outputs into array
// elements block SROA -- VGPR_Count=88 proved it).  Volatile inline-asm
// global_load_dwordx4 into named SSA values cannot sink and cannot spill
// silently.  One asm s_waitcnt vmcnt(0) per 64-step block.  Loop body has
// zero loads.  Lane l holds dp[2l], dp[2l+1]; lane 63 also dp[128].
// ---------------------------------------------------------------------------
__global__ __launch_bounds__(64, 1)
void ctc_scan_kernel(const float4* __restrict__ oddS,   // [B*128][64]
                     const float*  __restrict__ blankS, // [B][T]
                     const int*    __restrict__ label,  // [U][B]
                     const int*    __restrict__ blank_ptr,
                     float* __restrict__ out,           // [B][T][LABT] align
                     float* __restrict__ loss_out)      // [B]
{
    __shared__ __align__(16) unsigned long long bpm[NT][4]; // backptr masks
    __shared__ int   wl[NT];
    __shared__ float fdp[132];

    const int b = blockIdx.x;
    const int l = threadIdx.x;
    const int blank = blank_ptr[0];

    // label-derived state
    int raw = label[l * NB + b];
    unsigned long long nbmask = __ballot(raw != blank);
    const int Y = 2 * (int)__popcll(nbmask) + 1;
    int ev  = (raw == blank) ? -1 : raw;
    int pev = __shfl_up(ev, 1);
    if (l == 0) pev = -1;
    const bool cndO = (ev == blank) || (ev == pev);   // cond for odd j=2l+1

    const char*  epb = (const char*)(oddS + (size_t)b * 128 * 64);  // [t4][l]
    const float* bS  = blankS + (size_t)b * NT;

    // blank stream: bv_k[lane l] = blank[64k + l]  (pinned by first WAITVM0)
    float bv0 = bS[l],       bv1 = bS[64 + l],  bv2 = bS[128 + l],
          bv3 = bS[192 + l], bv4 = bS[256 + l], bv5 = bS[320 + l],
          bv6 = bS[384 + l], bv7 = bS[448 + l];

#define ASM_LD(dst, addr, imm)                                                 \
    asm volatile("global_load_dwordx4 %0, %1, off offset:" #imm                \
                 : "=v"(dst) : "v"(addr))

// load block nb (16 t4-rows) into 16 NAMED f32x4 regs; volatile -> no sink,
// named SSA outputs -> no alloca/scratch.
#define PF16(nb, d0,d1,d2,d3,d4,d5,d6,d7,d8,d9,d10,d11,d12,d13,d14,d15)       \
    do {                                                                       \
        const char* g0_ = epb + (((nb) * 16 + 0)  * 64 + l) * 16;              \
        const char* g1_ = epb + (((nb) * 16 + 4)  * 64 + l) * 16;              \
        const char* g2_ = epb + (((nb) * 16 + 8)  * 64 + l) * 16;              \
        const char* g3_ = epb + (((nb) * 16 + 12) * 64 + l) * 16;              \
        ASM_LD(d0,  g0_, 0);    ASM_LD(d1,  g0_, 1024);                        \
        ASM_LD(d2,  g0_, 2048); ASM_LD(d3,  g0_, 3072);                        \
        ASM_LD(d4,  g1_, 0);    ASM_LD(d5,  g1_, 1024);                        \
        ASM_LD(d6,  g1_, 2048); ASM_LD(d7,  g1_, 3072);                        \
        ASM_LD(d8,  g2_, 0);    ASM_LD(d9,  g2_, 1024);                        \
        ASM_LD(d10, g2_, 2048); ASM_LD(d11, g2_, 3072);                        \
        ASM_LD(d12, g3_, 0);    ASM_LD(d13, g3_, 1024);                        \
        ASM_LD(d14, g3_, 2048); ASM_LD(d15, g3_, 3072);                        \
        __builtin_amdgcn_sched_barrier(0);                                     \
    } while (0)

#define WAITVM0                                                                \
    do { asm volatile("s_waitcnt vmcnt(0)" ::: "memory");                      \
         __builtin_amdgcn_sched_barrier(0); } while (0)

#define RL(BV, i)                                                              \
    __int_as_float(__builtin_amdgcn_readlane(__float_as_int(BV), (i)))

    f32x4 a0,a1,a2,a3,a4,a5,a6,a7,a8,a9,a10,a11,a12,a13,a14,a15;
    f32x4 b0,b1,b2,b3,b4,b5,b6,b7,b8,b9,b10,b11,b12,b13,b14,b15;

    PF16(0, a0,a1,a2,a3,a4,a5,a6,a7,a8,a9,a10,a11,a12,a13,a14,a15);
    WAITVM0;                 // block 0 + bv* resident

    // t = 0 init: dp0[0] = blank[0], dp0[1] = odd[0][lane0], else PAD
    float v0 = (l == 0) ? bv0 : PADV;     // dp[2l]
    float v1 = (l == 0) ? a0[0] : PADV;   // dp[2l+1]
    float v2 = PADV;                      // dp[128] (lane 63 meaningful)

#define STEP_T(t_, evv, se)                                                    \
    do {                                                                       \
        float u1 = dpp_wave_shr1(v1, PADV);   /* dp[2l-1] */                   \
        /* even j=2l: 2-way lse (bit-exact 1-exp form) */                      \
        float mE   = fmaxf(v0, u1);                                            \
        float lseE = mE + logf(1.0f + expf(-fabsf(v0 - u1)));                  \
        unsigned long long bE = __ballot(v0 < u1);                             \
        /* odd j=2l+1: 3-way lse, exact rounds-0..6 expression */              \
        float c2e = cndO ? PADV : u1;                                          \
        float mO  = fmaxf(fmaxf(v1, v0), c2e);                                 \
        float lseO = mO + logf(expf(v1 - mO) + expf(v0 - mO) + expf(c2e - mO));\
        unsigned long long gAB = __ballot(v1 >= v0);                           \
        unsigned long long gAC = __ballot(v1 >= c2e);                          \
        unsigned long long gBC = __ballot(v0 >= c2e);                          \
        /* j=128: 2-way lse on lane63's (v2, v1) */                            \
        float mL   = fmaxf(v2, v1);                                            \
        float lseL = mL + logf(1.0f + expf(-fabsf(v2 - v1)));                  \
        unsigned long long bL = __ballot(v2 < v1);                             \
        v0 = (se) + lseE;                                                      \
        v1 = (evv) + lseO;                                                     \
        v2 = (se) + lseL;                                                      \
        if (l == 0) {                                                          \
            unsigned long long t0m = gAB & gAC;                                \
            ulonglong2 w01, w23;                                               \
            w01.x = bE;          w01.y = ~t0m & gBC;                           \
            w23.x = ~t0m & ~gBC; w23.y = (bL >> 63);                           \
            *(ulonglong2*)&bpm[t_][0] = w01;                                   \
            *(ulonglong2*)&bpm[t_][2] = w23;                                   \
        }                                                                      \
    } while (0)

#define STEP4(tb, cc, BV)                                                      \
    do {                                                                       \
        STEP_T((tb) + 0, cc[0], RL(BV, ((tb) + 0) & 63));                      \
        STEP_T((tb) + 1, cc[1], RL(BV, ((tb) + 1) & 63));                      \
        STEP_T((tb) + 2, cc[2], RL(BV, ((tb) + 2) & 63));                      \
        STEP_T((tb) + 3, cc[3], RL(BV, ((tb) + 3) & 63));                      \
    } while (0)

#define B64(base, C0,C1,C2,C3,C4,C5,C6,C7,C8,C9,C10,C11,C12,C13,C14,C15, BV)  \
    do {                                                                       \
        STEP4((base) + 0,  C0,  BV); STEP4((base) + 4,  C1,  BV);              \
        STEP4((base) + 8,  C2,  BV); STEP4((base) + 12, C3,  BV);              \
        STEP4((base) + 16, C4,  BV); STEP4((base) + 20, C5,  BV);              \
        STEP4((base) + 24, C6,  BV); STEP4((base) + 28, C7,  BV);              \
        STEP4((base) + 32, C8,  BV); STEP4((base) + 36, C9,  BV);              \
        STEP4((base) + 40, C10, BV); STEP4((base) + 44, C11, BV);              \
        STEP4((base) + 48, C12, BV); STEP4((base) + 52, C13, BV);              \
        STEP4((base) + 56, C14, BV); STEP4((base) + 60, C15, BV);              \
    } while (0)

    // ---- block 0 (t = 1..63): prefetch block 1 into b*, compute a* ----
    PF16(1, b0,b1,b2,b3,b4,b5,b6,b7,b8,b9,b10,b11,b12,b13,b14,b15);
    STEP_T(1, a0[1], RL(bv0, 1));
    STEP_T(2, a0[2], RL(bv0, 2));
    STEP_T(3, a0[3], RL(bv0, 3));
    STEP4(4,  a1,  bv0); STEP4(8,  a2,  bv0); STEP4(12, a3,  bv0);
    STEP4(16, a4,  bv0); STEP4(20, a5,  bv0); STEP4(24, a6,  bv0);
    STEP4(28, a7,  bv0); STEP4(32, a8,  bv0); STEP4(36, a9,  bv0);
    STEP4(40, a10, bv0); STEP4(44, a11, bv0); STEP4(48, a12, bv0);
    STEP4(52, a13, bv0); STEP4(56, a14, bv0); STEP4(60, a15, bv0);
    WAITVM0;
    // ---- blocks 1..6: alternate buffers ----
    PF16(2, a0,a1,a2,a3,a4,a5,a6,a7,a8,a9,a10,a11,a12,a13,a14,a15);
    B64(64,  b0,b1,b2,b3,b4,b5,b6,b7,b8,b9,b10,b11,b12,b13,b14,b15, bv1);
    WAITVM0;
    PF16(3, b0,b1,b2,b3,b4,b5,b6,b7,b8,b9,b10,b11,b12,b13,b14,b15);
    B64(128, a0,a1,a2,a3,a4,a5,a6,a7,a8,a9,a10,a11,a12,a13,a14,a15, bv2);
    WAITVM0;
    PF16(4, a0,a1,a2,a3,a4,a5,a6,a7,a8,a9,a10,a11,a12,a13,a14,a15);
    B64(192, b0,b1,b2,b3,b4,b5,b6,b7,b8,b9,b10,b11,b12,b13,b14,b15, bv3);
    WAITVM0;
    PF16(5, b0,b1,b2,b3,b4,b5,b6,b7,b8,b9,b10,b11,b12,b13,b14,b15);
    B64(256, a0,a1,a2,a3,a4,a5,a6,a7,a8,a9,a10,a11,a12,a13,a14,a15, bv4);
    WAITVM0;
    PF16(6, a0,a1,a2,a3,a4,a5,a6,a7,a8,a9,a10,a11,a12,a13,a14,a15);
    B64(320, b0,b1,b2,b3,b4,b5,b6,b7,b8,b9,b10,b11,b12,b13,b14,b15, bv5);
    WAITVM0;
    PF16(7, b0,b1,b2,b3,b4,b5,b6,b7,b8,b9,b10,b11,b12,b13,b14,b15);
    B64(384, a0,a1,a2,a3,a4,a5,a6,a7,a8,a9,a10,a11,a12,a13,a14,a15, bv6);
    WAITVM0;
    // ---- block 7 (t = 448..511): no prefetch, no wait ----
    B64(448, b0,b1,b2,b3,b4,b5,b6,b7,b8,b9,b10,b11,b12,b13,b14,b15, bv7);
#undef B64
#undef STEP4
#undef STEP_T

    // publish final dp row
    fdp[2 * l]     = v0;
    fdp[2 * l + 1] = v1;
    if (l == 63) fdp[128] = v2;
    __syncthreads();

    // zero-fill align output (overlaps with lane0 backtrack drain)
    float* outA = out + (size_t)b * (NT * LABT);
    {
        float4 z4; z4.x = 0.f; z4.y = 0.f; z4.z = 0.f; z4.w = 0.f;
        float4* o4 = (float4*)outA;
        for (int p = l; p < (NT * LABT) / 4; p += 64) o4[p] = z4;
    }

    // loss + register-ring Viterbi backtrack (lane 0)
    if (l == 0) {
        int i2 = Y - 2; if (i2 < 0) i2 += LABT;   // python wrap for yl==1
        float d1 = fdp[Y - 1];
        float d2 = fdp[i2];
        float mm = fmaxf(d1, d2);
        float la = mm + logf(expf(d1 - mm) + expf(d2 - mm));
        loss_out[b] = -la * 2.0f / (float)(Y - 1);

        int w = (d1 > d2) ? (Y - 1) : i2;
        const ulonglong2* bp2 = (const ulonglong2*)&bpm[0][0];  // 2 per row

#define BLOAD(qa, qb, row) do { qa = bp2[2 * (row)]; qb = bp2[2 * (row) + 1]; } while (0)
#define BPROC(qa, qb, row) do {                                                \
        wl[row] = w;                                                           \
        int lw_ = w >> 1;                                                      \
        int dE_ = (w == 128) ? (int)qb.y : (int)((qa.x >> lw_) & 1ULL);        \
        int dO_ = (int)((qa.y >> lw_) & 1ULL) + 2 * (int)((qb.x >> lw_) & 1ULL);\
        w -= (w & 1) ? dO_ : dE_;                                              \
    } while (0)

        ulonglong2 a0_, b0_, a1_, b1_, a2_, b2_, a3_, b3_;
        BLOAD(a0_, b0_, NT - 1);
        BLOAD(a1_, b1_, NT - 2);
        BLOAD(a2_, b2_, NT - 3);
        BLOAD(a3_, b3_, NT - 4);
        int tt;
        for (tt = NT - 1; tt >= 8; tt -= 4) {
            BPROC(a0_, b0_, tt    ); BLOAD(a0_, b0_, tt - 4);
            BPROC(a1_, b1_, tt - 1); BLOAD(a1_, b1_, tt - 5);
            BPROC(a2_, b2_, tt - 2); BLOAD(a2_, b2_, tt - 6);
            BPROC(a3_, b3_, tt - 3); BLOAD(a3_, b3_, tt - 7);
        }
        // slots now hold rows 7,6,5,4
        BPROC(a0_, b0_, 7); BLOAD(a0_, b0_, 3);
        BPROC(a1_, b1_, 6); BLOAD(a1_, b1_, 2);
        BPROC(a2_, b2_, 5); BLOAD(a2_, b2_, 1);
        BPROC(a3_, b3_, 4);
        BPROC(a0_, b0_, 3);
        BPROC(a1_, b1_, 2);
        BPROC(a2_, b2_, 1);
        wl[0] = w;   // bp at t=0 is identity
#undef BLOAD
#undef BPROC
    }
    __syncthreads();   // drain zero stores + publish wl

    // scatter the ones
    for (int t2 = l; t2 < NT; t2 += 64)
        outA[(size_t)t2 * LABT + wl[t2]] = 1.0f;
}

// ---------------------------------------------------------------------------
extern "C" void kernel_launch(void* const* d_in, const int* in_sizes, int n_in,
                              void* d_out, int out_size, void* d_ws, size_t ws_size,
                              hipStream_t stream)
{
    const float* logit = (const float*)d_in[0];
    const int*   label = (const int*)d_in[1];
    const int*   blank = (const int*)d_in[2];

    float* out = (float*)d_out;   // [B*T*LABT] align (0/1 float) then [B] loss

    float4* oddS   = (float4*)d_ws;                        // 4.19 MB
    float*  blankS = (float*)((char*)d_ws + (size_t)NB * 128 * 64 * 16); // 64 KB

    ctc_gather_kernel<<<(NB * 128 * 64) / 256, 256, 0, stream>>>(
        logit, label, blank, oddS, blankS);
    ctc_scan_kernel<<<NB, 64, 0, stream>>>(
        oddS, blankS, label, blank, out, out + (size_t)NB * NT * LABT);
}